// Round 2
// baseline (1407.682 us; speedup 1.0000x reference)
//
#include <hip/hip_runtime.h>

#define WN 4096   // nodes per level
#define BN 256    // batch
#define KN 8      // parents per node
#define NLVL 15   // levels after the prior
#define NBLK 256  // one block per CU
#define NTHR 1024 // 16 waves

// Monotonic grid barrier. Counter in d_ws, zeroed each launch by hipMemsetAsync.
// Device-scope atomics + __threadfence give cross-XCD visibility (G16).
__device__ __forceinline__ void grid_bar(unsigned* bar, unsigned syncno) {
  __syncthreads();
  if (threadIdx.x == 0) {
    __threadfence();                 // release: my block's writes -> coherent point
    atomicAdd(bar, 1u);
    const unsigned target = syncno * NBLK;
    while (atomicAdd(bar, 0u) < target) __builtin_amdgcn_s_sleep(2);
  }
  __syncthreads();
  __threadfence();                   // acquire: don't read stale lines
}

__global__ __launch_bounds__(NTHR, 4) void fused_kernel(
    const float* __restrict__ obs, const float* __restrict__ pw,
    const float* __restrict__ pb,  const float* __restrict__ wts,
    const float* __restrict__ bia, const int* __restrict__ par,
    const int* __restrict__ inv,   float* __restrict__ out,
    float* hA, float* hB, unsigned* bar) {
  __shared__ float tile[32][33];
  const int tx = threadIdx.x & 31;
  const int ty = threadIdx.x >> 5;   // 0..31
  unsigned syncno = 0;

  // ---- phase 0: hA[n*BN+b] = relu(obs[b*WN+n]*pw[n]+pb[n]), tiled transpose ----
  for (int i = 0; i < 4; ++i) {
    const int t  = blockIdx.x * 4 + i;      // 1024 tiles of 32x32
    const int n0 = (t & 127) * 32;
    const int b0 = (t >> 7) * 32;
    tile[ty][tx] = fmaxf(fmaf(obs[(size_t)(b0 + ty) * WN + n0 + tx],
                              pw[n0 + tx], pb[n0 + tx]), 0.0f);
    __syncthreads();
    hA[(n0 + ty) * BN + b0 + tx] = tile[tx][ty];
    __syncthreads();
  }
  grid_bar(bar, ++syncno);

  // ---- phase 1: 15 levels; wave = node, lane covers 4 batch elems (float4) ----
  const int w    = threadIdx.x >> 6;          // 0..15
  const int lane = threadIdx.x & 63;
  const int n    = blockIdx.x * 16 + w;       // 256*16 = 4096 nodes
  const int b4   = lane * 4;

  const float* hin = hA;
  float*      hout = hB;
  for (int l = 0; l < NLVL; ++l) {
    const size_t nl = (size_t)l * WN + n;
    const int4   p0 = *(const int4*)(par + nl * KN);
    const int4   p1 = *(const int4*)(par + nl * KN + 4);
    const float4 w0 = *(const float4*)(wts + nl * KN);
    const float4 w1 = *(const float4*)(wts + nl * KN + 4);
    const float  bb = bia[nl];
    const bool   iv = inv[nl] != 0;

    float4 x0 = *(const float4*)(hin + p0.x * BN + b4);
    float4 x1 = *(const float4*)(hin + p0.y * BN + b4);
    float4 x2 = *(const float4*)(hin + p0.z * BN + b4);
    float4 x3 = *(const float4*)(hin + p0.w * BN + b4);
    float4 x4 = *(const float4*)(hin + p1.x * BN + b4);
    float4 x5 = *(const float4*)(hin + p1.y * BN + b4);
    float4 x6 = *(const float4*)(hin + p1.z * BN + b4);
    float4 x7 = *(const float4*)(hin + p1.w * BN + b4);
    if (iv) {  // wave-uniform branch
      x0.x=1.f-x0.x; x0.y=1.f-x0.y; x0.z=1.f-x0.z; x0.w=1.f-x0.w;
      x1.x=1.f-x1.x; x1.y=1.f-x1.y; x1.z=1.f-x1.z; x1.w=1.f-x1.w;
      x2.x=1.f-x2.x; x2.y=1.f-x2.y; x2.z=1.f-x2.z; x2.w=1.f-x2.w;
      x3.x=1.f-x3.x; x3.y=1.f-x3.y; x3.z=1.f-x3.z; x3.w=1.f-x3.w;
      x4.x=1.f-x4.x; x4.y=1.f-x4.y; x4.z=1.f-x4.z; x4.w=1.f-x4.w;
      x5.x=1.f-x5.x; x5.y=1.f-x5.y; x5.z=1.f-x5.z; x5.w=1.f-x5.w;
      x6.x=1.f-x6.x; x6.y=1.f-x6.y; x6.z=1.f-x6.z; x6.w=1.f-x6.w;
      x7.x=1.f-x7.x; x7.y=1.f-x7.y; x7.z=1.f-x7.z; x7.w=1.f-x7.w;
    }
    float4 acc = {bb, bb, bb, bb};
    acc.x = fmaf(x0.x, w0.x, acc.x); acc.y = fmaf(x0.y, w0.x, acc.y);
    acc.z = fmaf(x0.z, w0.x, acc.z); acc.w = fmaf(x0.w, w0.x, acc.w);
    acc.x = fmaf(x1.x, w0.y, acc.x); acc.y = fmaf(x1.y, w0.y, acc.y);
    acc.z = fmaf(x1.z, w0.y, acc.z); acc.w = fmaf(x1.w, w0.y, acc.w);
    acc.x = fmaf(x2.x, w0.z, acc.x); acc.y = fmaf(x2.y, w0.z, acc.y);
    acc.z = fmaf(x2.z, w0.z, acc.z); acc.w = fmaf(x2.w, w0.z, acc.w);
    acc.x = fmaf(x3.x, w0.w, acc.x); acc.y = fmaf(x3.y, w0.w, acc.y);
    acc.z = fmaf(x3.z, w0.w, acc.z); acc.w = fmaf(x3.w, w0.w, acc.w);
    acc.x = fmaf(x4.x, w1.x, acc.x); acc.y = fmaf(x4.y, w1.x, acc.y);
    acc.z = fmaf(x4.z, w1.x, acc.z); acc.w = fmaf(x4.w, w1.x, acc.w);
    acc.x = fmaf(x5.x, w1.y, acc.x); acc.y = fmaf(x5.y, w1.y, acc.y);
    acc.z = fmaf(x5.z, w1.y, acc.z); acc.w = fmaf(x5.w, w1.y, acc.w);
    acc.x = fmaf(x6.x, w1.z, acc.x); acc.y = fmaf(x6.y, w1.z, acc.y);
    acc.z = fmaf(x6.z, w1.z, acc.z); acc.w = fmaf(x6.w, w1.z, acc.w);
    acc.x = fmaf(x7.x, w1.w, acc.x); acc.y = fmaf(x7.y, w1.w, acc.y);
    acc.z = fmaf(x7.z, w1.w, acc.z); acc.w = fmaf(x7.w, w1.w, acc.w);
    acc.x = fmaxf(acc.x, 0.f); acc.y = fmaxf(acc.y, 0.f);
    acc.z = fmaxf(acc.z, 0.f); acc.w = fmaxf(acc.w, 0.f);
    *(float4*)(hout + n * BN + b4) = acc;

    grid_bar(bar, ++syncno);
    const float* t2 = hout; hout = (float*)hin; hin = t2;
  }
  // after loop hin == hB (final state)

  // ---- phase 2: out[b*WN+n] = hin[n*BN+b], tiled transpose ----
  for (int i = 0; i < 4; ++i) {
    const int t  = blockIdx.x * 4 + i;
    const int n0 = (t & 127) * 32;
    const int b0 = (t >> 7) * 32;
    tile[ty][tx] = hin[(n0 + ty) * BN + b0 + tx];
    __syncthreads();
    out[(size_t)(b0 + ty) * WN + n0 + tx] = tile[tx][ty];
    __syncthreads();
  }
}

extern "C" void kernel_launch(void* const* d_in, const int* in_sizes, int n_in,
                              void* d_out, int out_size, void* d_ws, size_t ws_size,
                              hipStream_t stream) {
  const float* obs = (const float*)d_in[0];
  const float* pw  = (const float*)d_in[1];
  const float* pb  = (const float*)d_in[2];
  const float* wts = (const float*)d_in[3];
  const float* bia = (const float*)d_in[4];
  const int*   par = (const int*)d_in[5];
  const int*   inv = (const int*)d_in[6];
  float* out = (float*)d_out;

  unsigned* bar = (unsigned*)d_ws;                    // barrier counter (zeroed below)
  float* hA = (float*)((char*)d_ws + 4096);           // 4 MB ping
  float* hB = hA + (size_t)WN * BN;                   // 4 MB pong

  hipMemsetAsync(d_ws, 0, 4096, stream);              // zero barrier counter

  void* args[] = {(void*)&obs, (void*)&pw, (void*)&pb, (void*)&wts, (void*)&bia,
                  (void*)&par, (void*)&inv, (void*)&out, (void*)&hA, (void*)&hB,
                  (void*)&bar};
  hipLaunchCooperativeKernel((const void*)fused_kernel, dim3(NBLK), dim3(NTHR),
                             args, 0, stream);
}

// Round 3
// 129.590 us; speedup vs baseline: 10.8625x; 10.8625x over previous
//
#include <hip/hip_runtime.h>

#define WN 4096   // nodes per level
#define BN 256    // batch
#define KN 8      // parents per node
#define NLVL 15   // levels after the prior
#define BSPLIT 2  // batch columns per block
#define NBLK (BN / BSPLIT)   // 128 blocks
#define NTHR 1024            // 16 waves
#define NPT (WN / NTHR)      // 4 nodes per thread

// Entire 15-level chain is block-local: a block owns BSPLIT batch columns and
// keeps ALL 4096 node activations for them in LDS (dependencies are only
// across nodes, never across batch). No grid sync, no global h traffic.
__global__ __launch_bounds__(NTHR) void fused_lds_kernel(
    const float* __restrict__ obs, const float* __restrict__ pw,
    const float* __restrict__ pb,  const float* __restrict__ wts,
    const float* __restrict__ bia, const int* __restrict__ par,
    const int* __restrict__ inv,   float* __restrict__ out) {
  __shared__ float h[2][BSPLIT][WN];   // 64 KB, double-buffered
  const int t  = threadIdx.x;
  const int b0 = blockIdx.x * BSPLIT;

  // ---- init: h0[c][n] = relu(obs[b0+c][n]*pw[n]+pb[n]); coalesced over n ----
#pragma unroll
  for (int i = 0; i < NPT; ++i) {
    const int n  = i * NTHR + t;
    const float w = pw[n], bb = pb[n];
#pragma unroll
    for (int c = 0; c < BSPLIT; ++c)
      h[0][c][n] = fmaxf(fmaf(obs[(size_t)(b0 + c) * WN + n], w, bb), 0.0f);
  }
  __syncthreads();

  // ---- 15 levels, all in LDS ----
  int cur = 0;
  for (int l = 0; l < NLVL; ++l) {
    const float* wl = wts + (size_t)l * WN * KN;
    const int*   pl = par + (size_t)l * WN * KN;
    const float* bl = bia + (size_t)l * WN;
    const int*   il = inv + (size_t)l * WN;
    const float* hc0 = h[cur][0];
    const float* hc1 = h[cur][1];
    float*       hn0 = h[cur ^ 1][0];
    float*       hn1 = h[cur ^ 1][1];
#pragma unroll
    for (int i = 0; i < NPT; ++i) {
      const int n = i * NTHR + t;                  // lane-consecutive -> coalesced params
      const int4   p0 = *(const int4*)(pl + (size_t)n * KN);
      const int4   p1 = *(const int4*)(pl + (size_t)n * KN + 4);
      float4       w0 = *(const float4*)(wl + (size_t)n * KN);
      float4       w1 = *(const float4*)(wl + (size_t)n * KN + 4);
      const float  bb = bl[n];
      const bool   iv = il[n] != 0;
      // fold inversion into params: sum_k w_k*(iv?1-x:x) = (iv?sum(w):0) + sum_k (iv?-w:w)*x
      const float ws  = ((w0.x + w0.y) + (w0.z + w0.w)) + ((w1.x + w1.y) + (w1.z + w1.w));
      const float base = iv ? bb + ws : bb;
      const float s    = iv ? -1.0f : 1.0f;
      w0.x *= s; w0.y *= s; w0.z *= s; w0.w *= s;
      w1.x *= s; w1.y *= s; w1.z *= s; w1.w *= s;

      float a0 = base, a1 = base;                  // one acc per batch column
      a0 = fmaf(hc0[p0.x], w0.x, a0);  a1 = fmaf(hc1[p0.x], w0.x, a1);
      a0 = fmaf(hc0[p0.y], w0.y, a0);  a1 = fmaf(hc1[p0.y], w0.y, a1);
      a0 = fmaf(hc0[p0.z], w0.z, a0);  a1 = fmaf(hc1[p0.z], w0.z, a1);
      a0 = fmaf(hc0[p0.w], w0.w, a0);  a1 = fmaf(hc1[p0.w], w0.w, a1);
      a0 = fmaf(hc0[p1.x], w1.x, a0);  a1 = fmaf(hc1[p1.x], w1.x, a1);
      a0 = fmaf(hc0[p1.y], w1.y, a0);  a1 = fmaf(hc1[p1.y], w1.y, a1);
      a0 = fmaf(hc0[p1.z], w1.z, a0);  a1 = fmaf(hc1[p1.z], w1.z, a1);
      a0 = fmaf(hc0[p1.w], w1.w, a0);  a1 = fmaf(hc1[p1.w], w1.w, a1);

      hn0[n] = fmaxf(a0, 0.0f);                    // writes: lane-consecutive banks, conflict-free
      hn1[n] = fmaxf(a1, 0.0f);
    }
    __syncthreads();   // next level reads the buffer we just wrote
    cur ^= 1;
  }

  // ---- output: out[b0+c][n] = h_final[c][n]; coalesced over n ----
#pragma unroll
  for (int i = 0; i < NPT; ++i) {
    const int n = i * NTHR + t;
#pragma unroll
    for (int c = 0; c < BSPLIT; ++c)
      out[(size_t)(b0 + c) * WN + n] = h[cur][c][n];
  }
}

extern "C" void kernel_launch(void* const* d_in, const int* in_sizes, int n_in,
                              void* d_out, int out_size, void* d_ws, size_t ws_size,
                              hipStream_t stream) {
  const float* obs = (const float*)d_in[0];
  const float* pw  = (const float*)d_in[1];
  const float* pb  = (const float*)d_in[2];
  const float* wts = (const float*)d_in[3];
  const float* bia = (const float*)d_in[4];
  const int*   par = (const int*)d_in[5];
  const int*   inv = (const int*)d_in[6];
  float* out = (float*)d_out;

  fused_lds_kernel<<<NBLK, NTHR, 0, stream>>>(obs, pw, pb, wts, bia, par, inv, out);
}

// Round 4
// 116.426 us; speedup vs baseline: 12.0908x; 1.1131x over previous
//
#include <hip/hip_runtime.h>

#define WN 4096   // nodes per level
#define BN 256    // batch
#define KN 8      // parents per node
#define NLVL 15   // levels after the prior
#define NTHR 1024 // 16 waves
#define NPT (WN / NTHR)

// ---- pre-pack params into d_ws (runs every launch; d_ws is re-poisoned) ----
// Wp: float4[NLVL*WN*2] signed weights (inv folded in)
// Pp: uint4 [NLVL*WN]   8 x u16 parents
// Bz: float [NLVL*WN]   base = bias + iv*sum(w)
__global__ __launch_bounds__(256) void prep_kernel(
    const float* __restrict__ wts, const float* __restrict__ bia,
    const int* __restrict__ par,   const int* __restrict__ inv,
    float4* __restrict__ Wp, uint4* __restrict__ Pp, float* __restrict__ Bz) {
  const int idx = blockIdx.x * 256 + threadIdx.x;   // over NLVL*WN
  const float4 w0 = *(const float4*)(wts + (size_t)idx * KN);
  const float4 w1 = *(const float4*)(wts + (size_t)idx * KN + 4);
  const int4   p0 = *(const int4*)(par + (size_t)idx * KN);
  const int4   p1 = *(const int4*)(par + (size_t)idx * KN + 4);
  const bool   iv = inv[idx] != 0;
  const float  ws = ((w0.x + w0.y) + (w0.z + w0.w)) + ((w1.x + w1.y) + (w1.z + w1.w));
  const float  s  = iv ? -1.0f : 1.0f;
  Wp[(size_t)idx * 2]     = make_float4(w0.x * s, w0.y * s, w0.z * s, w0.w * s);
  Wp[(size_t)idx * 2 + 1] = make_float4(w1.x * s, w1.y * s, w1.z * s, w1.w * s);
  uint4 pp;
  pp.x = (unsigned)p0.x | ((unsigned)p0.y << 16);
  pp.y = (unsigned)p0.z | ((unsigned)p0.w << 16);
  pp.z = (unsigned)p1.x | ((unsigned)p1.y << 16);
  pp.w = (unsigned)p1.z | ((unsigned)p1.w << 16);
  Pp[idx] = pp;
  Bz[idx] = iv ? bia[idx] + ws : bia[idx];
}

// ---- main: one block per batch column; whole 15-level chain in 32KB LDS ----
__global__ __launch_bounds__(NTHR) void fused_lds_kernel(
    const float* __restrict__ obs, const float* __restrict__ pw,
    const float* __restrict__ pb,  const float4* __restrict__ Wp,
    const uint4* __restrict__ Pp,  const float* __restrict__ Bz,
    float* __restrict__ out) {
  __shared__ float h[2][WN];   // 32 KB double-buffered state for ONE batch column
  const int    t = threadIdx.x;
  const size_t b = blockIdx.x;

#pragma unroll
  for (int i = 0; i < NPT; ++i) {
    const int n = i * NTHR + t;
    h[0][n] = fmaxf(fmaf(obs[b * WN + n], pw[n], pb[n]), 0.0f);
  }
  __syncthreads();

  int cur = 0;
  for (int l = 0; l < NLVL; ++l) {
    const float* hc = h[cur];
    float*       hn = h[cur ^ 1];
    const size_t lb = (size_t)l * WN;
#pragma unroll
    for (int i = 0; i < NPT; ++i) {
      const int    n  = i * NTHR + t;         // lane-consecutive -> coalesced params
      const size_t nl = lb + n;
      const uint4  pp = Pp[nl];
      const float4 w0 = Wp[nl * 2];
      const float4 w1 = Wp[nl * 2 + 1];
      float acc = Bz[nl];
      acc = fmaf(hc[pp.x & 0xffffu], w0.x, acc);
      acc = fmaf(hc[pp.x >> 16],     w0.y, acc);
      acc = fmaf(hc[pp.y & 0xffffu], w0.z, acc);
      acc = fmaf(hc[pp.y >> 16],     w0.w, acc);
      acc = fmaf(hc[pp.z & 0xffffu], w1.x, acc);
      acc = fmaf(hc[pp.z >> 16],     w1.y, acc);
      acc = fmaf(hc[pp.w & 0xffffu], w1.z, acc);
      acc = fmaf(hc[pp.w >> 16],     w1.w, acc);
      hn[n] = fmaxf(acc, 0.0f);
    }
    __syncthreads();
    cur ^= 1;
  }

#pragma unroll
  for (int i = 0; i < NPT; ++i) {
    const int n = i * NTHR + t;
    out[b * WN + n] = h[cur][n];
  }
}

extern "C" void kernel_launch(void* const* d_in, const int* in_sizes, int n_in,
                              void* d_out, int out_size, void* d_ws, size_t ws_size,
                              hipStream_t stream) {
  const float* obs = (const float*)d_in[0];
  const float* pw  = (const float*)d_in[1];
  const float* pb  = (const float*)d_in[2];
  const float* wts = (const float*)d_in[3];
  const float* bia = (const float*)d_in[4];
  const int*   par = (const int*)d_in[5];
  const int*   inv = (const int*)d_in[6];
  float* out = (float*)d_out;

  // d_ws layout (≈3.2 MB): Wp | Pp | Bz
  char* ws = (char*)d_ws;
  float4* Wp = (float4*)ws;                                     // 15*4096*32 B
  uint4*  Pp = (uint4*)(ws + (size_t)NLVL * WN * 32);           // 15*4096*16 B
  float*  Bz = (float*)(ws + (size_t)NLVL * WN * 48);           // 15*4096*4 B

  prep_kernel<<<(NLVL * WN) / 256, 256, 0, stream>>>(wts, bia, par, inv, Wp, Pp, Bz);
  fused_lds_kernel<<<BN, NTHR, 0, stream>>>(obs, pw, pb, Wp, Pp, Bz, out);
}

// Round 6
// 111.047 us; speedup vs baseline: 12.6765x; 1.0484x over previous
//
#include <hip/hip_runtime.h>

#define WN 4096   // nodes per level
#define BN 256    // batch
#define KN 8      // parents per node
#define NLVL 15   // levels after the prior
#define NTHR 1024 // 16 waves
#define NPT (WN / NTHR)

// ---- pre-pack params into d_ws (runs every launch; d_ws is re-poisoned) ----
// Wp: float4[NLVL*WN*2] signed weights (inv folded in)
// Pp: uint4 [NLVL*WN]   8 x u16 parents
// Bz: float [NLVL*WN]   base = bias + iv*sum(w)
__global__ __launch_bounds__(256) void prep_kernel(
    const float* __restrict__ wts, const float* __restrict__ bia,
    const int* __restrict__ par,   const int* __restrict__ inv,
    float4* __restrict__ Wp, uint4* __restrict__ Pp, float* __restrict__ Bz) {
  const int idx = blockIdx.x * 256 + threadIdx.x;   // over NLVL*WN
  const float4 w0 = *(const float4*)(wts + (size_t)idx * KN);
  const float4 w1 = *(const float4*)(wts + (size_t)idx * KN + 4);
  const int4   p0 = *(const int4*)(par + (size_t)idx * KN);
  const int4   p1 = *(const int4*)(par + (size_t)idx * KN + 4);
  const bool   iv = inv[idx] != 0;
  const float  ws = ((w0.x + w0.y) + (w0.z + w0.w)) + ((w1.x + w1.y) + (w1.z + w1.w));
  const float  s  = iv ? -1.0f : 1.0f;
  Wp[(size_t)idx * 2]     = make_float4(w0.x * s, w0.y * s, w0.z * s, w0.w * s);
  Wp[(size_t)idx * 2 + 1] = make_float4(w1.x * s, w1.y * s, w1.z * s, w1.w * s);
  uint4 pp;
  pp.x = (unsigned)p0.x | ((unsigned)p0.y << 16);
  pp.y = (unsigned)p0.z | ((unsigned)p0.w << 16);
  pp.z = (unsigned)p1.x | ((unsigned)p1.y << 16);
  pp.w = (unsigned)p1.z | ((unsigned)p1.w << 16);
  Pp[idx] = pp;
  Bz[idx] = iv ? bia[idx] + ws : bia[idx];
}

// ---- main: one block per batch column; 15-level chain in 32KB LDS.
// Parents/base software-pipelined across the level barrier (double-buffered
// registers, compile-time indices via full unroll); weights issued before the
// gather block so L2 traffic overlaps the ds_read stream.
__global__ __launch_bounds__(NTHR) void fused_lds_kernel(
    const float* __restrict__ obs, const float* __restrict__ pw,
    const float* __restrict__ pb,  const float4* __restrict__ Wp,
    const uint4* __restrict__ Pp,  const float* __restrict__ Bz,
    float* __restrict__ out) {
  __shared__ float h[2][WN];
  const int    t = threadIdx.x;
  const size_t b = blockIdx.x;

  uint4 pp[2][NPT];
  float bz[2][NPT];

  // prefetch level-0 parents/base while doing the init pass
#pragma unroll
  for (int i = 0; i < NPT; ++i) {
    pp[0][i] = Pp[i * NTHR + t];
    bz[0][i] = Bz[i * NTHR + t];
  }
#pragma unroll
  for (int i = 0; i < NPT; ++i) {
    const int n = i * NTHR + t;
    h[0][n] = fmaxf(fmaf(obs[b * WN + n], pw[n], pb[n]), 0.0f);
  }
  __syncthreads();

#pragma unroll
  for (int l = 0; l < NLVL; ++l) {
    const int cb = l & 1;        // compile-time after unroll
    const int nb = cb ^ 1;
    const float* hc = h[l & 1];
    float*       hn = h[(l + 1) & 1];

    // 1) prefetch NEXT level's parents/base (h-independent) — in flight
    //    through this whole level's compute.
    if (l + 1 < NLVL) {
#pragma unroll
      for (int i = 0; i < NPT; ++i) {
        const size_t nl = (size_t)(l + 1) * WN + i * NTHR + t;
        pp[nb][i] = Pp[nl];
        bz[nb][i] = Bz[nl];
      }
    }

    // 2) current level's weights — issued before the gathers so the L2 reads
    //    run concurrently with the LDS pipe.
    float4 w0[NPT], w1[NPT];
#pragma unroll
    for (int i = 0; i < NPT; ++i) {
      const size_t nl = (size_t)l * WN + i * NTHR + t;
      w0[i] = Wp[nl * 2];
      w1[i] = Wp[nl * 2 + 1];
    }

    // 3) gathers + fma (parents already in registers from previous level)
#pragma unroll
    for (int i = 0; i < NPT; ++i) {
      const uint4 p = pp[cb][i];
      const float x0 = hc[p.x & 0xffffu];
      const float x1 = hc[p.x >> 16];
      const float x2 = hc[p.y & 0xffffu];
      const float x3 = hc[p.y >> 16];
      const float x4 = hc[p.z & 0xffffu];
      const float x5 = hc[p.z >> 16];
      const float x6 = hc[p.w & 0xffffu];
      const float x7 = hc[p.w >> 16];
      float acc = bz[cb][i];
      acc = fmaf(x0, w0[i].x, acc);
      acc = fmaf(x1, w0[i].y, acc);
      acc = fmaf(x2, w0[i].z, acc);
      acc = fmaf(x3, w0[i].w, acc);
      acc = fmaf(x4, w1[i].x, acc);
      acc = fmaf(x5, w1[i].y, acc);
      acc = fmaf(x6, w1[i].z, acc);
      acc = fmaf(x7, w1[i].w, acc);
      hn[i * NTHR + t] = fmaxf(acc, 0.0f);
    }
    __syncthreads();
  }

#pragma unroll
  for (int i = 0; i < NPT; ++i) {
    const int n = i * NTHR + t;
    out[b * WN + n] = h[NLVL & 1][n];
  }
}

extern "C" void kernel_launch(void* const* d_in, const int* in_sizes, int n_in,
                              void* d_out, int out_size, void* d_ws, size_t ws_size,
                              hipStream_t stream) {
  const float* obs = (const float*)d_in[0];
  const float* pw  = (const float*)d_in[1];
  const float* pb  = (const float*)d_in[2];
  const float* wts = (const float*)d_in[3];
  const float* bia = (const float*)d_in[4];
  const int*   par = (const int*)d_in[5];
  const int*   inv = (const int*)d_in[6];
  float* out = (float*)d_out;

  // d_ws layout (≈3.2 MB): Wp | Pp | Bz
  char* ws = (char*)d_ws;
  float4* Wp = (float4*)ws;                                     // 15*4096*32 B
  uint4*  Pp = (uint4*)(ws + (size_t)NLVL * WN * 32);           // 15*4096*16 B
  float*  Bz = (float*)(ws + (size_t)NLVL * WN * 48);           // 15*4096*4 B

  prep_kernel<<<(NLVL * WN) / 256, 256, 0, stream>>>(wts, bia, par, inv, Wp, Pp, Bz);
  fused_lds_kernel<<<BN, NTHR, 0, stream>>>(obs, pw, pb, Wp, Pp, Bz, out);
}